// Round 1
// baseline (3730.290 us; speedup 1.0000x reference)
//
#include <hip/hip_runtime.h>
#include <hip/hip_fp16.h>

#define NB 128
#define NT 1024
#define DIN 64
#define NP 128
#define NG 512
#define NO 64

#ifndef __has_builtin
#define __has_builtin(x) 0
#endif
#if __has_builtin(__builtin_amdgcn_fdot2)
#define HAVE_FDOT2 1
#else
#define HAVE_FDOT2 0
#endif

typedef _Float16 h2v __attribute__((ext_vector_type(2)));

__device__ __forceinline__ float sigf(float x) {
  return 1.0f / (1.0f + __expf(-x));
}
// tanh via exp, safe for large |x| (no inf/inf)
__device__ __forceinline__ float tanh_fast(float x) {
  float ax = fabsf(x);
  float e = __expf(-2.0f * ax);
  float t = (1.0f - e) / (1.0f + e);
  return copysignf(t, x);
}

__device__ __forceinline__ unsigned packh2(float a, float b) {
  return (unsigned)__half_as_ushort(__float2half_rn(a)) |
         ((unsigned)__half_as_ushort(__float2half_rn(b)) << 16);
}

__device__ __forceinline__ float dot2(unsigned wu, unsigned xu, float acc) {
#if HAVE_FDOT2
  return __builtin_amdgcn_fdot2(__builtin_bit_cast(h2v, wu),
                                __builtin_bit_cast(h2v, xu), acc, false);
#else
  float wl = __half2float(__ushort_as_half((unsigned short)(wu & 0xffffu)));
  float wh = __half2float(__ushort_as_half((unsigned short)(wu >> 16)));
  float xl = __half2float(__ushort_as_half((unsigned short)(xu & 0xffffu)));
  float xh = __half2float(__ushort_as_half((unsigned short)(xu >> 16)));
  return fmaf(wh, xh, fmaf(wl, xl, acc));
#endif
}

// ---------------- Layer 0: x[B,T,64] -> h0[B,T,128] (f16) ----------------
// 1 block per batch row; thread r owns gate-row r (weights in VGPRs).
__global__ __launch_bounds__(512, 2) void lstm_l0(
    const float* __restrict__ x,
    const float* __restrict__ wih_g,   // [512,64]
    const float* __restrict__ whh_g,   // [512,128]
    const float* __restrict__ bih,     // [512] (layer 0 slice)
    const float* __restrict__ bhh,
    __half* __restrict__ h0out)        // [B,T,128]
{
  const int b = blockIdx.x;
  const int r = threadIdx.x;

  float wih[DIN];
  float whh[NP];
#pragma unroll
  for (int k = 0; k < DIN / 4; ++k)
    *(float4*)&wih[4 * k] = *(const float4*)&wih_g[r * DIN + 4 * k];
#pragma unroll
  for (int k = 0; k < NP / 4; ++k)
    *(float4*)&whh[4 * k] = *(const float4*)&whh_g[r * NP + 4 * k];
  const float bias = bih[r] + bhh[r];

  __shared__ __align__(16) float xb[2][DIN];
  __shared__ __align__(16) float hs[NP];
  __shared__ __align__(16) float gs[NG];

  if (r < NP) hs[r] = 0.0f;
  if (r < 16) *(float4*)&xb[0][4 * r] = *(const float4*)&x[(size_t)b * NT * DIN + 4 * r];
  float c = 0.0f;
  __syncthreads();

  float4 xpre;
  for (int t = 0; t < NT; ++t) {
    // prefetch next timestep's x into registers (hidden under the dot phase)
    if (r < 16 && t + 1 < NT)
      xpre = *(const float4*)&x[(size_t)b * NT * DIN + (size_t)(t + 1) * DIN + 4 * r];

    float a0 = bias, a1 = 0.f, a2 = 0.f, a3 = 0.f;
    const float4* xc = (const float4*)xb[t & 1];
#pragma unroll
    for (int k = 0; k < DIN / 4; ++k) {
      float4 v = xc[k];
      a0 = fmaf(wih[4 * k + 0], v.x, a0);
      a1 = fmaf(wih[4 * k + 1], v.y, a1);
      a2 = fmaf(wih[4 * k + 2], v.z, a2);
      a3 = fmaf(wih[4 * k + 3], v.w, a3);
    }
    const float4* hc = (const float4*)hs;
#pragma unroll
    for (int k = 0; k < NP / 4; ++k) {
      float4 v = hc[k];
      a0 = fmaf(whh[4 * k + 0], v.x, a0);
      a1 = fmaf(whh[4 * k + 1], v.y, a1);
      a2 = fmaf(whh[4 * k + 2], v.z, a2);
      a3 = fmaf(whh[4 * k + 3], v.w, a3);
    }
    gs[r] = (a0 + a1) + (a2 + a3);
    __syncthreads();  // gates ready; everyone done reading hs/xb

    if (r < NP) {  // waves 0-1: cell update
      float gi = gs[r], gf = gs[r + NP], gg = gs[r + 2 * NP], go = gs[r + 3 * NP];
      float ii = sigf(gi), ff = sigf(gf), oo = sigf(go);
      float g2 = tanh_fast(gg);
      c = ff * c + ii * g2;
      float h = oo * tanh_fast(c);
      hs[r] = h;
      h0out[(size_t)b * NT * NP + (size_t)t * NP + r] = __float2half(h);
    }
    if (r < 16 && t + 1 < NT)
      *(float4*)&xb[(t + 1) & 1][4 * r] = xpre;
    __syncthreads();  // h_t and x_{t+1} staged
  }
}

// ------------- Layer 1 + FC: h0[B,T,128](f16) -> out[B,T,64](f32) -------------
// w_ih1 packed f16 pairs (64 VGPRs) + w_hh1 f32 (128 VGPRs) per thread.
__global__ __launch_bounds__(512, 2) void lstm_l1_fc(
    const __half* __restrict__ h0,
    const float* __restrict__ wih_g,   // [512,128]
    const float* __restrict__ whh_g,   // [512,128]
    const float* __restrict__ bih,     // [512] (layer 1 slice)
    const float* __restrict__ bhh,
    const float* __restrict__ fcw_g,   // [64,128]
    const float* __restrict__ fcb_g,   // [64]
    float* __restrict__ out)           // [B,T,64]
{
  const int b = blockIdx.x;
  const int r = threadIdx.x;

  unsigned wih[NP / 2];  // packed f16 pairs
#pragma unroll
  for (int k = 0; k < NP / 4; ++k) {
    float4 v = *(const float4*)&wih_g[r * NP + 4 * k];
    wih[2 * k + 0] = packh2(v.x, v.y);
    wih[2 * k + 1] = packh2(v.z, v.w);
  }
  float whh[NP];
#pragma unroll
  for (int k = 0; k < NP / 4; ++k)
    *(float4*)&whh[4 * k] = *(const float4*)&whh_g[r * NP + 4 * k];
  const float bias = bih[r] + bhh[r];

  __shared__ __align__(16) unsigned xb[2][NP / 2];  // h0_t packed pairs
  __shared__ __align__(16) float hs[NP];
  __shared__ __align__(16) float gs[NG];
  __shared__ float fcw[NO][NP + 1];  // +1 pad: bank (o+c)%32
  __shared__ float fcp[NO][5];       // 4 partials + pad

  for (int i = r; i < NO * NP; i += 512) fcw[i >> 7][i & (NP - 1)] = fcw_g[i];
  float fcb = (r < NO) ? fcb_g[r] : 0.f;
  if (r < NP) hs[r] = 0.f;
  if (r < 16) *(uint4*)&xb[0][4 * r] = *(const uint4*)&h0[(size_t)b * NT * NP + 8 * r];
  float c = 0.f;
  __syncthreads();

  uint4 xpre;
  for (int t = 0; t < NT; ++t) {
    if (r < 16 && t + 1 < NT)
      xpre = *(const uint4*)&h0[(size_t)b * NT * NP + (size_t)(t + 1) * NP + 8 * r];

    float a0 = bias, a1 = 0.f, a2 = 0.f, a3 = 0.f;
    const uint4* xc = (const uint4*)xb[t & 1];
#pragma unroll
    for (int k = 0; k < 16; ++k) {  // 64 packed pairs = 128 inputs
      uint4 u = xc[k];
      a0 = dot2(wih[4 * k + 0], u.x, a0);
      a1 = dot2(wih[4 * k + 1], u.y, a1);
      a2 = dot2(wih[4 * k + 2], u.z, a2);
      a3 = dot2(wih[4 * k + 3], u.w, a3);
    }
    const float4* hc = (const float4*)hs;
#pragma unroll
    for (int k = 0; k < NP / 4; ++k) {
      float4 v = hc[k];
      a0 = fmaf(whh[4 * k + 0], v.x, a0);
      a1 = fmaf(whh[4 * k + 1], v.y, a1);
      a2 = fmaf(whh[4 * k + 2], v.z, a2);
      a3 = fmaf(whh[4 * k + 3], v.w, a3);
    }
    gs[r] = (a0 + a1) + (a2 + a3);
    __syncthreads();  // B: gates ready

    if (r < NP) {
      float gi = gs[r], gf = gs[r + NP], gg = gs[r + 2 * NP], go = gs[r + 3 * NP];
      float ii = sigf(gi), ff = sigf(gf), oo = sigf(go);
      float g2 = tanh_fast(gg);
      c = ff * c + ii * g2;
      float h = oo * tanh_fast(c);
      hs[r] = h;
    }
    __syncthreads();  // C: h_t ready

    if (r < 256) {  // FC partials: o = r&63, quarter q = r>>6 (wave-uniform q)
      int o = r & 63, q = r >> 6;
      float s = 0.f;
#pragma unroll
      for (int j = 0; j < 32; ++j)
        s = fmaf(fcw[o][32 * q + j], hs[32 * q + j], s);
      fcp[o][q] = s;
    }
    if (r < 16 && t + 1 < NT)
      *(uint4*)&xb[(t + 1) & 1][4 * r] = xpre;
    __syncthreads();  // D: partials + next h0 staged

    if (r < NO) {
      float s = ((fcp[r][0] + fcp[r][1]) + (fcp[r][2] + fcp[r][3])) + fcb;
      out[(size_t)b * NT * NO + (size_t)t * NO + r] = s;
    }
  }
}

extern "C" void kernel_launch(void* const* d_in, const int* in_sizes, int n_in,
                              void* d_out, int out_size, void* d_ws, size_t ws_size,
                              hipStream_t stream) {
  const float* x     = (const float*)d_in[0];
  const float* w_ih0 = (const float*)d_in[1];
  const float* w_hh0 = (const float*)d_in[2];
  const float* w_ih1 = (const float*)d_in[3];
  const float* w_hh1 = (const float*)d_in[4];
  const float* b_ih  = (const float*)d_in[5];  // [2,512]
  const float* b_hh  = (const float*)d_in[6];  // [2,512]
  const float* fc_w  = (const float*)d_in[7];
  const float* fc_b  = (const float*)d_in[8];
  float* out = (float*)d_out;

  __half* h0 = (__half*)d_ws;  // [B,T,128] f16 = 32 MB

  lstm_l0<<<NB, 512, 0, stream>>>(x, w_ih0, w_hh0, b_ih, b_hh, h0);
  lstm_l1_fc<<<NB, 512, 0, stream>>>(h0, w_ih1, w_hh1, b_ih + NG, b_hh + NG,
                                     fc_w, fc_b, out);
}